// Round 16
// baseline (955.052 us; speedup 1.0000x reference)
//
#include <hip/hip_runtime.h>

// Problem: x (B=4, C=256, D=32, H=64, W=64) fp32.
// 1) reflect-pad(2) + per-(b,c) mean  == weighted sum over original x
// 2) LSTMCell scan over C=256 channels (B=4, hidden=32, input=1)
// 3) gate[b,c] = sigmoid(h_c . gate_w + gate_b);  out = x * gate[b,c]
//
// R16: hide the LSTM under the mean pass. K1 = 2049 blocks:
//   ticket 0   -> LSTM block (4 waves = 4 batches). SINGLE spinner: polls
//                 per-(b,c) counters written by mean blocks, consumes means
//                 in production order, writes gates (plain stores; kernel
//                 boundary publishes them to K2).
//   tickets 1+ -> mean half-channels in C-MAJOR ascending order (c, then b,
//                 then half) so all 4 LSTM waves consume in lockstep with
//                 production. Producers NEVER wait (R10/R12/R14 lesson: only
//                 a single spinning block is safe).
// K2 = scale, C-MAJOR DESCENDING (mirrored serpentine: mean ends at c=255,
// scale starts there; scale ends at c=0, next replay's mean starts there).
// NT stores (R8/R11 A/B). __launch_bounds__(256,8) keeps mean occupancy
// 8/CU; lstm branch may spill - one hidden block, irrelevant.

#define MEAN_DEN (1.0f / 166464.0f)   // 36*68*68

typedef unsigned int uint;
typedef float f32x4 __attribute__((ext_vector_type(4)));
typedef float f32x2 __attribute__((ext_vector_type(2)));

__device__ __forceinline__ float sigf(float x) {
    return 1.0f / (1.0f + __expf(-x));
}
__device__ __forceinline__ float tanh_fast(float x) {
    return fmaf(2.0f, sigf(2.0f * x), -1.0f);   // tanh(x) = 2*sigmoid(2x) - 1
}
__device__ __forceinline__ uint ld_acq(const uint* p) {
    return __hip_atomic_load(p, __ATOMIC_ACQUIRE, __HIP_MEMORY_SCOPE_AGENT);
}

#define RL(v, k) __builtin_bit_cast(float, \
    __builtin_amdgcn_readlane(__builtin_bit_cast(int, (v)), (k)))
#define DW(k) const float w0_##k = W_hh[r0 * 32 + (k)]; \
              const float w1_##k = W_hh[r1 * 32 + (k)];
#define GK(k, A0, A1) { const float hk = RL(h, k); \
                A0 = fmaf(hk, w0_##k, A0); A1 = fmaf(hk, w1_##k, A1); }

// ws layout (4B units): [0] ticket | [64..1088) cnt[c*4+b] | [2048..4096)
// part[(c*4+b)*2+half] | [6400..7424) gates[b*256+c]
__global__ __launch_bounds__(256, 8) void meanlstm_kernel(
    const float* __restrict__ x,
    const float* __restrict__ W_ih, const float* __restrict__ W_hh,
    const float* __restrict__ b_ih, const float* __restrict__ b_hh,
    const float* __restrict__ gate_w, const float* __restrict__ gate_b,
    float* __restrict__ ws)
{
    uint*  ctrl  = (uint*)ws;
    uint*  cnt   = (uint*)ws + 64;
    float* part  = ws + 2048;
    float* gates = ws + 6400;

    __shared__ float red[256];
    __shared__ uint s_t;

    const int tid = threadIdx.x;
    if (tid == 0)
        s_t = __hip_atomic_fetch_add(ctrl, 1u, __ATOMIC_RELAXED,
                                     __HIP_MEMORY_SCOPE_AGENT);
    __syncthreads();
    const uint T = s_t;

    if (T == 0u) {
        // ---------- LSTM role: 4 independent waves, wave b = batch b ----------
        const int b = tid >> 6, l = tid & 63;
        const int r0 = l, r1 = l + 64;
        const float wih0 = W_ih[r0], wih1 = W_ih[r1];
        const float bias0 = b_ih[r0] + b_hh[r0];
        const float bias1 = b_ih[r1] + b_hh[r1];
        DW(0)  DW(1)  DW(2)  DW(3)  DW(4)  DW(5)  DW(6)  DW(7)
        DW(8)  DW(9)  DW(10) DW(11) DW(12) DW(13) DW(14) DW(15)
        DW(16) DW(17) DW(18) DW(19) DW(20) DW(21) DW(22) DW(23)
        DW(24) DW(25) DW(26) DW(27) DW(28) DW(29) DW(30) DW(31)
        const float gwl = gate_w[l & 31];
        const float gb = gate_b[0];

        float h = 0.0f, cst = 0.0f;
        for (int c = 0; c < 256; c++) {
            // wait for both halves of (b,c); wave-uniform poll, single reader
            while (ld_acq(&cnt[c * 4 + b]) < 2u) __builtin_amdgcn_s_sleep(8);
            const f32x2 pr = *(const f32x2*)&part[(c * 4 + b) * 2];
            const float inp = (pr.x + pr.y) * MEAN_DEN;
            float a0 = fmaf(inp, wih0, bias0), b0 = 0.f, c0 = 0.f, d0 = 0.f;
            float a1 = fmaf(inp, wih1, bias1), b1 = 0.f, c1 = 0.f, d1 = 0.f;
            GK(0,a0,a1)  GK(1,b0,b1)  GK(2,c0,c1)  GK(3,d0,d1)
            GK(4,a0,a1)  GK(5,b0,b1)  GK(6,c0,c1)  GK(7,d0,d1)
            GK(8,a0,a1)  GK(9,b0,b1)  GK(10,c0,c1) GK(11,d0,d1)
            GK(12,a0,a1) GK(13,b0,b1) GK(14,c0,c1) GK(15,d0,d1)
            GK(16,a0,a1) GK(17,b0,b1) GK(18,c0,c1) GK(19,d0,d1)
            GK(20,a0,a1) GK(21,b0,b1) GK(22,c0,c1) GK(23,d0,d1)
            GK(24,a0,a1) GK(25,b0,b1) GK(26,c0,c1) GK(27,d0,d1)
            GK(28,a0,a1) GK(29,b0,b1) GK(30,c0,c1) GK(31,d0,d1)
            const float z0 = (a0 + b0) + (c0 + d0);
            const float z1 = (a1 + b1) + (c1 + d1);
            float zf, zo;
#if __has_builtin(__builtin_amdgcn_permlane32_swap)
            {
                auto ra = __builtin_amdgcn_permlane32_swap(
                    __builtin_bit_cast(uint, z0), __builtin_bit_cast(uint, z0), false, false);
                auto rb = __builtin_amdgcn_permlane32_swap(
                    __builtin_bit_cast(uint, z1), __builtin_bit_cast(uint, z1), false, false);
                zf = __builtin_bit_cast(float, ra[1]);
                zo = __builtin_bit_cast(float, rb[1]);
            }
#else
            zf = __shfl_xor(z0, 32);
            zo = __shfl_xor(z1, 32);
#endif
            // valid in lanes<32 only (high lanes: finite garbage, never read)
            cst = sigf(zf) * cst + sigf(z0) * tanh_fast(z1);
            h = sigf(zo) * tanh_fast(cst);
            float p = h * gwl;   // inline gate reduce over lanes 0..31
            p += __shfl_xor(p, 1);  p += __shfl_xor(p, 2);  p += __shfl_xor(p, 4);
            p += __shfl_xor(p, 8);  p += __shfl_xor(p, 16);
            if (l == 0) gates[b * 256 + c] = sigf(p + gb);   // plain store:
            // kernel completion orders gates for the scale dispatch.
        }
        return;
    }

    // ---------- mean role: item = T-1, C-MAJOR ascending ----------
    // item encodes (c, b, half): c = item>>3, b = (item>>1)&3, half = item&1
    const int item = (int)T - 1;
    const int c = item >> 3, b = (item >> 1) & 3, half = item & 1;
    const int ch = b * 256 + c;
    const f32x4* __restrict__ p = (const f32x4*)x + ((size_t)ch << 15) + (half << 14);
    const int base = half << 14;

    float s0 = 0.0f, s1 = 0.0f, s2 = 0.0f, s3 = 0.0f;
#pragma unroll
    for (int g = 0; g < 8; g++) {
        f32x4 v[8];
#pragma unroll
        for (int u = 0; u < 8; u++) v[u] = p[g * 2048 + u * 256 + tid];
#pragma unroll
        for (int u = 0; u < 8; u++) {
            const int i = base + g * 2048 + u * 256 + tid;
            const int q = i & 15;             // f4 index within W-row
            const int hh = (i >> 4) & 63;
            const int d = i >> 10;
            float t = (v[u].x + v[u].y) + (v[u].z + v[u].w);
            if (q == 0 || q == 15) t += v[u].y + v[u].z;   // W 1,2,61,62 doubled
            const float wd = ((d == 1) | (d == 2) | (d == 29) | (d == 30)) ? 2.0f : 1.0f;
            const float wh = ((hh == 1) | (hh == 2) | (hh == 61) | (hh == 62)) ? 2.0f : 1.0f;
            const float w = wd * wh;
            if ((u & 3) == 0)      s0 = fmaf(w, t, s0);
            else if ((u & 3) == 1) s1 = fmaf(w, t, s1);
            else if ((u & 3) == 2) s2 = fmaf(w, t, s2);
            else                   s3 = fmaf(w, t, s3);
        }
    }
    red[tid] = (s0 + s1) + (s2 + s3);
    __syncthreads();
    for (int s = 128; s > 0; s >>= 1) {
        if (tid < s) red[tid] += red[tid + s];
        __syncthreads();
    }
    if (tid == 0) {
        part[item] = red[0];                 // (c*4+b)*2 + half == item
        // release: part store visible before the counter increment
        __hip_atomic_fetch_add(&cnt[c * 4 + b], 1u, __ATOMIC_RELEASE,
                               __HIP_MEMORY_SCOPE_AGENT);
    }
}

// ---------- Kernel 2: out = x * gate[ch], C-MAJOR DESCENDING, NT stores ----------
__global__ __launch_bounds__(256) void scale_kernel(const float* __restrict__ x,
                                                    const float* __restrict__ ws,
                                                    float* __restrict__ out) {
    const float* gates = ws + 6400;
    const int item = 2047 - (int)blockIdx.x;       // descending c-major walk
    const int c = item >> 3, b = (item >> 1) & 3, half = item & 1;
    const int ch = b * 256 + c;
    const float g = gates[ch];
    const size_t off = ((size_t)ch << 15) + (half << 14);
    const f32x4* __restrict__ xi = (const f32x4*)x + off;
    f32x4* __restrict__ oi = (f32x4*)out + off;
    const int tid = threadIdx.x;
#pragma unroll
    for (int gr = 0; gr < 8; gr++) {
        f32x4 v[8];
#pragma unroll
        for (int u = 0; u < 8; u++) v[u] = xi[gr * 2048 + u * 256 + tid];
#pragma unroll
        for (int u = 0; u < 8; u++) {
            v[u] *= g;
            __builtin_nontemporal_store(v[u], &oi[gr * 2048 + u * 256 + tid]);
        }
    }
}

extern "C" void kernel_launch(void* const* d_in, const int* in_sizes, int n_in,
                              void* d_out, int out_size, void* d_ws, size_t ws_size,
                              hipStream_t stream) {
    const float* x      = (const float*)d_in[0];
    const float* W_ih   = (const float*)d_in[1];   // (128,1)
    const float* W_hh   = (const float*)d_in[2];   // (128,32)
    const float* b_ih   = (const float*)d_in[3];   // (128,)
    const float* b_hh   = (const float*)d_in[4];   // (128,)
    const float* gate_w = (const float*)d_in[5];   // (1,32)
    const float* gate_b = (const float*)d_in[6];   // (1,)
    float* out = (float*)d_out;
    float* ws  = (float*)d_ws;

    // reset ticket + counters every call (capture-safe, deterministic)
    hipMemsetAsync(d_ws, 0, 8192, stream);
    meanlstm_kernel<<<2049, 256, 0, stream>>>(x, W_ih, W_hh, b_ih, b_hh,
                                              gate_w, gate_b, ws);
    scale_kernel<<<2048, 256, 0, stream>>>(x, ws, out);
}

// Round 17
// 374.975 us; speedup vs baseline: 2.5470x; 2.5470x over previous
//
#include <hip/hip_runtime.h>

// Problem: x (B=4, C=256, D=32, H=64, W=64) fp32.
// 1) reflect-pad(2) + per-(b,c) mean  == weighted sum over original x
// 2) LSTMCell scan over C=256 channels (B=4, hidden=32, input=1)
// 3) gate[b,c] = sigmoid(h_c . gate_w + gate_b);  out = x * gate[b,c]
//
// R17 = R15 (best, 350us: serpentine order + NT stores) + packed-fp32 LSTM:
// the (z0,z1) row-pair accumulates as f32x2 so the 64 scalar v_fma_f32 per
// step become 32 v_pk_fma_f32 (MI355X dual-rate fp32), shrinking the
// issue-bound recurrence ~200->~130 cyc/step. All sync schemes (R6 coop,
// R10/R12/R14/R16 spin) lost 2-50x -- plain ordered dispatches only.

#define MEAN_DEN (1.0f / 166464.0f)   // 36*68*68

typedef unsigned int uint;
typedef float f32x4 __attribute__((ext_vector_type(4)));
typedef float f32x2 __attribute__((ext_vector_type(2)));

__device__ __forceinline__ float sigf(float x) {
    return 1.0f / (1.0f + __expf(-x));
}
__device__ __forceinline__ float tanh_fast(float x) {
    return fmaf(2.0f, sigf(2.0f * x), -1.0f);   // tanh(x) = 2*sigmoid(2x) - 1
}

// ---------- Kernel 1: weighted half-channel partial sums, DESCENDING ----------
// 2048 blocks (8/CU, 100% occupancy); 8 independent loads in flight/thread.
__global__ __launch_bounds__(256) void mean_kernel(const float* __restrict__ x,
                                                   float* __restrict__ part) {
    const int bid = 2047 - (int)blockIdx.x;        // descending walk over x
    const int ch = bid >> 1, half = bid & 1;
    const f32x4* __restrict__ p = (const f32x4*)x + (size_t)ch * 32768 + half * 16384;
    const int base = half * 16384;
    const int tid = threadIdx.x;

    float s0 = 0.0f, s1 = 0.0f, s2 = 0.0f, s3 = 0.0f;
#pragma unroll
    for (int g = 0; g < 8; g++) {
        f32x4 v[8];
#pragma unroll
        for (int u = 0; u < 8; u++) v[u] = p[g * 2048 + u * 256 + tid];
#pragma unroll
        for (int u = 0; u < 8; u++) {
            const int i = base + g * 2048 + u * 256 + tid;
            const int q = i & 15;             // f4 index within W-row
            const int hh = (i >> 4) & 63;
            const int d = i >> 10;
            float t = (v[u].x + v[u].y) + (v[u].z + v[u].w);
            if (q == 0 || q == 15) t += v[u].y + v[u].z;   // W 1,2,61,62 doubled
            const float wd = ((d == 1) | (d == 2) | (d == 29) | (d == 30)) ? 2.0f : 1.0f;
            const float wh = ((hh == 1) | (hh == 2) | (hh == 61) | (hh == 62)) ? 2.0f : 1.0f;
            const float w = wd * wh;
            if ((u & 3) == 0)      s0 = fmaf(w, t, s0);
            else if ((u & 3) == 1) s1 = fmaf(w, t, s1);
            else if ((u & 3) == 2) s2 = fmaf(w, t, s2);
            else                   s3 = fmaf(w, t, s3);
        }
    }
    float sum = (s0 + s1) + (s2 + s3);

    __shared__ float red[256];
    red[tid] = sum;
    __syncthreads();
    for (int s = 128; s > 0; s >>= 1) {
        if (tid < s) red[tid] += red[tid + s];
        __syncthreads();
    }
    if (tid == 0) part[bid] = red[0];
}

// ---------- Kernel 2: LSTM scan, 4 single-wave blocks, packed fp32 ----------
// Lane l owns gate rows l and l+64 (l<32: i,g ; l>=32: f,o). h register-
// resident; broadcast via v_readlane; i/f<->g/o via permlane32_swap.
// Row-pair (z0,z1) packed as f32x2 -> v_pk_fma_f32 (dual-rate fp32).
#define RL(v, k) __builtin_bit_cast(float, \
    __builtin_amdgcn_readlane(__builtin_bit_cast(int, (v)), (k)))
#define DW(k) f32x2 w_##k; w_##k.x = W_hh[r0 * 32 + (k)]; \
              w_##k.y = W_hh[r1 * 32 + (k)];
#define GK(k, ACC) { const float hk = RL(h, k); ACC += hk * w_##k; }

__global__ __launch_bounds__(64, 1) void lstm_kernel(
    const float* __restrict__ part,
    const float* __restrict__ W_ih, const float* __restrict__ W_hh,
    const float* __restrict__ b_ih, const float* __restrict__ b_hh,
    const float* __restrict__ gate_w, const float* __restrict__ gate_b,
    float* __restrict__ gates)
{
    __shared__ float cs[256];
    __shared__ float hist[257 * 33];     // stride-33: conflict-free epilogue reads

    const int b = blockIdx.x;            // batch 0..3
    const int l = threadIdx.x;           // lane 0..63
    const int r0 = l, r1 = l + 64;

    f32x2 wih; wih.x = W_ih[r0]; wih.y = W_ih[r1];
    f32x2 bias; bias.x = b_ih[r0] + b_hh[r0]; bias.y = b_ih[r1] + b_hh[r1];
    DW(0)  DW(1)  DW(2)  DW(3)  DW(4)  DW(5)  DW(6)  DW(7)
    DW(8)  DW(9)  DW(10) DW(11) DW(12) DW(13) DW(14) DW(15)
    DW(16) DW(17) DW(18) DW(19) DW(20) DW(21) DW(22) DW(23)
    DW(24) DW(25) DW(26) DW(27) DW(28) DW(29) DW(30) DW(31)

    // combine half-channel partials -> channel means for this batch
    const f32x2* __restrict__ p2 = (const f32x2*)part + b * 256;
#pragma unroll
    for (int j = 0; j < 4; j++) {
        const int cch = j * 64 + l;
        f32x2 pr = p2[cch];
        cs[cch] = (pr.x + pr.y) * MEAN_DEN;
    }

    float h = 0.0f, cstate = 0.0f;
    for (int t = 0; t < 256; t++) {
        const float inp = cs[t];
        // 4 independent packed accumulators: chain 8 deep, 32 pk-FMA issue
        f32x2 A = bias + inp * wih;
        f32x2 Bv = {0.f, 0.f}, Cv = {0.f, 0.f}, Dv = {0.f, 0.f};
        GK(0,A)  GK(1,Bv)  GK(2,Cv)  GK(3,Dv)
        GK(4,A)  GK(5,Bv)  GK(6,Cv)  GK(7,Dv)
        GK(8,A)  GK(9,Bv)  GK(10,Cv) GK(11,Dv)
        GK(12,A) GK(13,Bv) GK(14,Cv) GK(15,Dv)
        GK(16,A) GK(17,Bv) GK(18,Cv) GK(19,Dv)
        GK(20,A) GK(21,Bv) GK(22,Cv) GK(23,Dv)
        GK(24,A) GK(25,Bv) GK(26,Cv) GK(27,Dv)
        GK(28,A) GK(29,Bv) GK(30,Cv) GK(31,Dv)
        const f32x2 Z = (A + Bv) + (Cv + Dv);
        const float z0 = Z.x, z1 = Z.y;
        float zf, zo;
#if __has_builtin(__builtin_amdgcn_permlane32_swap)
        {
            auto ra = __builtin_amdgcn_permlane32_swap(
                __builtin_bit_cast(uint, z0), __builtin_bit_cast(uint, z0), false, false);
            auto rb = __builtin_amdgcn_permlane32_swap(
                __builtin_bit_cast(uint, z1), __builtin_bit_cast(uint, z1), false, false);
            zf = __builtin_bit_cast(float, ra[1]);
            zo = __builtin_bit_cast(float, rb[1]);
        }
#else
        zf = __shfl_xor(z0, 32);
        zo = __shfl_xor(z1, 32);
#endif
        // valid in lanes<32 only (high lanes compute finite garbage, never read)
        cstate = sigf(zf) * cstate + sigf(z0) * tanh_fast(z1);
        h = sigf(zo) * tanh_fast(cstate);
        if (l < 32) hist[(t + 1) * 33 + l] = h;   // off critical path
    }

    // deferred output gates: lane handles t = l, l+64, l+128, l+192
    const float gb = gate_b[0];
#pragma unroll
    for (int chunk = 0; chunk < 4; chunk++) {
        const int t = chunk * 64 + l;
        const float* hrow = &hist[(t + 1) * 33];
        float s = gb;
#pragma unroll
        for (int k = 0; k < 32; k++) s = fmaf(hrow[k], gate_w[k], s);
        gates[b * 256 + t] = sigf(s);
    }
}

// ---------- Kernel 3: out = x * gate[ch], ASCENDING, NT stores ----------
__global__ __launch_bounds__(256) void scale_kernel(const float* __restrict__ x,
                                                    const float* __restrict__ gates,
                                                    float* __restrict__ out) {
    const int bid = blockIdx.x;                    // ascending walk over x
    const int ch = bid >> 1, half = bid & 1;
    const float g = gates[ch];
    const size_t off = (size_t)ch * 32768 + half * 16384;
    const f32x4* __restrict__ xi = (const f32x4*)x + off;
    f32x4* __restrict__ oi = (f32x4*)out + off;
    const int tid = threadIdx.x;
#pragma unroll
    for (int gr = 0; gr < 8; gr++) {
        f32x4 v[8];
#pragma unroll
        for (int u = 0; u < 8; u++) v[u] = xi[gr * 2048 + u * 256 + tid];
#pragma unroll
        for (int u = 0; u < 8; u++) {
            v[u] *= g;
            __builtin_nontemporal_store(v[u], &oi[gr * 2048 + u * 256 + tid]);
        }
    }
}

extern "C" void kernel_launch(void* const* d_in, const int* in_sizes, int n_in,
                              void* d_out, int out_size, void* d_ws, size_t ws_size,
                              hipStream_t stream) {
    const float* x      = (const float*)d_in[0];
    const float* W_ih   = (const float*)d_in[1];   // (128,1)
    const float* W_hh   = (const float*)d_in[2];   // (128,32)
    const float* b_ih   = (const float*)d_in[3];   // (128,)
    const float* b_hh   = (const float*)d_in[4];   // (128,)
    const float* gate_w = (const float*)d_in[5];   // (1,32)
    const float* gate_b = (const float*)d_in[6];   // (1,)
    float* out = (float*)d_out;

    float* part  = (float*)d_ws;          // 2048 floats: half-channel partials
    float* gates = (float*)d_ws + 2048;   // 1024 floats

    mean_kernel<<<2048, 256, 0, stream>>>(x, part);
    lstm_kernel<<<4, 64, 0, stream>>>(part, W_ih, W_hh, b_ih, b_hh,
                                      gate_w, gate_b, gates);
    scale_kernel<<<2048, 256, 0, stream>>>(x, gates, out);
}

// Round 18
// 349.478 us; speedup vs baseline: 2.7328x; 1.0730x over previous
//
#include <hip/hip_runtime.h>

// Problem: x (B=4, C=256, D=32, H=64, W=64) fp32.
// 1) reflect-pad(2) + per-(b,c) mean  == weighted sum over original x
// 2) LSTMCell scan over C=256 channels (B=4, hidden=32, input=1)
// 3) gate[b,c] = sigmoid(h_c . gate_w + gate_b);  out = x * gate[b,c]
//
// R18 = EXACT REVERT to R15 (measured best, 350us): serpentine channel order
// (mean descending, scale ascending -> L3 aligns at both dispatch seams) +
// NT stores (R8/R11 A/B: -14us) + unroll-8 streams + scalar-FMA LSTM with
// readlane broadcast / permlane32_swap recombine / deferred output gates.
// R17's packed-f32x2 LSTM regressed (375us) -> reverted. All cross-block
// sync schemes (R6/R10/R12/R14/R16) lost 2-50x -> plain ordered dispatches.

#define MEAN_DEN (1.0f / 166464.0f)   // 36*68*68

typedef unsigned int uint;
typedef float f32x4 __attribute__((ext_vector_type(4)));
typedef float f32x2 __attribute__((ext_vector_type(2)));

__device__ __forceinline__ float sigf(float x) {
    return 1.0f / (1.0f + __expf(-x));
}
__device__ __forceinline__ float tanh_fast(float x) {
    return fmaf(2.0f, sigf(2.0f * x), -1.0f);   // tanh(x) = 2*sigmoid(2x) - 1
}

// ---------- Kernel 1: weighted half-channel partial sums, DESCENDING ----------
// 2048 blocks (8/CU, 100% occupancy); 8 independent loads in flight/thread.
__global__ __launch_bounds__(256) void mean_kernel(const float* __restrict__ x,
                                                   float* __restrict__ part) {
    const int bid = 2047 - (int)blockIdx.x;        // descending walk over x
    const int ch = bid >> 1, half = bid & 1;
    const f32x4* __restrict__ p = (const f32x4*)x + (size_t)ch * 32768 + half * 16384;
    const int base = half * 16384;
    const int tid = threadIdx.x;

    float s0 = 0.0f, s1 = 0.0f, s2 = 0.0f, s3 = 0.0f;
#pragma unroll
    for (int g = 0; g < 8; g++) {
        f32x4 v[8];
#pragma unroll
        for (int u = 0; u < 8; u++) v[u] = p[g * 2048 + u * 256 + tid];
#pragma unroll
        for (int u = 0; u < 8; u++) {
            const int i = base + g * 2048 + u * 256 + tid;
            const int q = i & 15;             // f4 index within W-row
            const int hh = (i >> 4) & 63;
            const int d = i >> 10;
            float t = (v[u].x + v[u].y) + (v[u].z + v[u].w);
            if (q == 0 || q == 15) t += v[u].y + v[u].z;   // W 1,2,61,62 doubled
            const float wd = ((d == 1) | (d == 2) | (d == 29) | (d == 30)) ? 2.0f : 1.0f;
            const float wh = ((hh == 1) | (hh == 2) | (hh == 61) | (hh == 62)) ? 2.0f : 1.0f;
            const float w = wd * wh;
            if ((u & 3) == 0)      s0 = fmaf(w, t, s0);
            else if ((u & 3) == 1) s1 = fmaf(w, t, s1);
            else if ((u & 3) == 2) s2 = fmaf(w, t, s2);
            else                   s3 = fmaf(w, t, s3);
        }
    }
    float sum = (s0 + s1) + (s2 + s3);

    __shared__ float red[256];
    red[tid] = sum;
    __syncthreads();
    for (int s = 128; s > 0; s >>= 1) {
        if (tid < s) red[tid] += red[tid + s];
        __syncthreads();
    }
    if (tid == 0) part[bid] = red[0];
}

// ---------- Kernel 2: LSTM scan, 4 single-wave blocks ----------
#define RL(v, k) __builtin_bit_cast(float, \
    __builtin_amdgcn_readlane(__builtin_bit_cast(int, (v)), (k)))
#define DW(k) const float w0_##k = W_hh[r0 * 32 + (k)]; \
              const float w1_##k = W_hh[r1 * 32 + (k)];
#define GK(k, A0, A1) { const float hk = RL(h, k); \
                A0 = fmaf(hk, w0_##k, A0); A1 = fmaf(hk, w1_##k, A1); }

__global__ __launch_bounds__(64, 1) void lstm_kernel(
    const float* __restrict__ part,
    const float* __restrict__ W_ih, const float* __restrict__ W_hh,
    const float* __restrict__ b_ih, const float* __restrict__ b_hh,
    const float* __restrict__ gate_w, const float* __restrict__ gate_b,
    float* __restrict__ gates)
{
    __shared__ float cs[256];
    __shared__ float hist[257 * 33];     // stride-33: conflict-free epilogue reads

    const int b = blockIdx.x;            // batch 0..3
    const int l = threadIdx.x;           // lane 0..63
    const int r0 = l, r1 = l + 64;

    const float wih0 = W_ih[r0];
    const float wih1 = W_ih[r1];
    const float bias0 = b_ih[r0] + b_hh[r0];
    const float bias1 = b_ih[r1] + b_hh[r1];
    DW(0)  DW(1)  DW(2)  DW(3)  DW(4)  DW(5)  DW(6)  DW(7)
    DW(8)  DW(9)  DW(10) DW(11) DW(12) DW(13) DW(14) DW(15)
    DW(16) DW(17) DW(18) DW(19) DW(20) DW(21) DW(22) DW(23)
    DW(24) DW(25) DW(26) DW(27) DW(28) DW(29) DW(30) DW(31)

    // combine half-channel partials -> channel means for this batch
    const f32x2* __restrict__ p2 = (const f32x2*)part + b * 256;
#pragma unroll
    for (int j = 0; j < 4; j++) {
        const int cch = j * 64 + l;
        f32x2 pr = p2[cch];
        cs[cch] = (pr.x + pr.y) * MEAN_DEN;
    }

    float h = 0.0f, cstate = 0.0f;
    for (int t = 0; t < 256; t++) {
        const float inp = cs[t];
        float a0 = fmaf(inp, wih0, bias0), b0 = 0.f, c0 = 0.f, d0 = 0.f;
        float a1 = fmaf(inp, wih1, bias1), b1 = 0.f, c1 = 0.f, d1 = 0.f;
        GK(0,a0,a1)  GK(1,b0,b1)  GK(2,c0,c1)  GK(3,d0,d1)
        GK(4,a0,a1)  GK(5,b0,b1)  GK(6,c0,c1)  GK(7,d0,d1)
        GK(8,a0,a1)  GK(9,b0,b1)  GK(10,c0,c1) GK(11,d0,d1)
        GK(12,a0,a1) GK(13,b0,b1) GK(14,c0,c1) GK(15,d0,d1)
        GK(16,a0,a1) GK(17,b0,b1) GK(18,c0,c1) GK(19,d0,d1)
        GK(20,a0,a1) GK(21,b0,b1) GK(22,c0,c1) GK(23,d0,d1)
        GK(24,a0,a1) GK(25,b0,b1) GK(26,c0,c1) GK(27,d0,d1)
        GK(28,a0,a1) GK(29,b0,b1) GK(30,c0,c1) GK(31,d0,d1)
        const float z0 = (a0 + b0) + (c0 + d0);
        const float z1 = (a1 + b1) + (c1 + d1);
        float zf, zo;
#if __has_builtin(__builtin_amdgcn_permlane32_swap)
        {
            auto ra = __builtin_amdgcn_permlane32_swap(
                __builtin_bit_cast(uint, z0), __builtin_bit_cast(uint, z0), false, false);
            auto rb = __builtin_amdgcn_permlane32_swap(
                __builtin_bit_cast(uint, z1), __builtin_bit_cast(uint, z1), false, false);
            zf = __builtin_bit_cast(float, ra[1]);
            zo = __builtin_bit_cast(float, rb[1]);
        }
#else
        zf = __shfl_xor(z0, 32);
        zo = __shfl_xor(z1, 32);
#endif
        // valid in lanes<32 only (high lanes compute finite garbage, never read)
        cstate = sigf(zf) * cstate + sigf(z0) * tanh_fast(z1);
        h = sigf(zo) * tanh_fast(cstate);
        if (l < 32) hist[(t + 1) * 33 + l] = h;   // off critical path
    }

    // deferred output gates: lane handles t = l, l+64, l+128, l+192
    const float gb = gate_b[0];
#pragma unroll
    for (int chunk = 0; chunk < 4; chunk++) {
        const int t = chunk * 64 + l;
        const float* hrow = &hist[(t + 1) * 33];
        float s = gb;
#pragma unroll
        for (int k = 0; k < 32; k++) s = fmaf(hrow[k], gate_w[k], s);
        gates[b * 256 + t] = sigf(s);
    }
}

// ---------- Kernel 3: out = x * gate[ch], ASCENDING, NT stores ----------
__global__ __launch_bounds__(256) void scale_kernel(const float* __restrict__ x,
                                                    const float* __restrict__ gates,
                                                    float* __restrict__ out) {
    const int bid = blockIdx.x;                    // ascending walk over x
    const int ch = bid >> 1, half = bid & 1;
    const float g = gates[ch];
    const size_t off = (size_t)ch * 32768 + half * 16384;
    const f32x4* __restrict__ xi = (const f32x4*)x + off;
    f32x4* __restrict__ oi = (f32x4*)out + off;
    const int tid = threadIdx.x;
#pragma unroll
    for (int gr = 0; gr < 8; gr++) {
        f32x4 v[8];
#pragma unroll
        for (int u = 0; u < 8; u++) v[u] = xi[gr * 2048 + u * 256 + tid];
#pragma unroll
        for (int u = 0; u < 8; u++) {
            v[u] *= g;
            __builtin_nontemporal_store(v[u], &oi[gr * 2048 + u * 256 + tid]);
        }
    }
}

extern "C" void kernel_launch(void* const* d_in, const int* in_sizes, int n_in,
                              void* d_out, int out_size, void* d_ws, size_t ws_size,
                              hipStream_t stream) {
    const float* x      = (const float*)d_in[0];
    const float* W_ih   = (const float*)d_in[1];   // (128,1)
    const float* W_hh   = (const float*)d_in[2];   // (128,32)
    const float* b_ih   = (const float*)d_in[3];   // (128,)
    const float* b_hh   = (const float*)d_in[4];   // (128,)
    const float* gate_w = (const float*)d_in[5];   // (1,32)
    const float* gate_b = (const float*)d_in[6];   // (1,)
    float* out = (float*)d_out;

    float* part  = (float*)d_ws;          // 2048 floats: half-channel partials
    float* gates = (float*)d_ws + 2048;   // 1024 floats

    mean_kernel<<<2048, 256, 0, stream>>>(x, part);
    lstm_kernel<<<4, 64, 0, stream>>>(part, W_ih, W_hh, b_ih, b_hh,
                                      gate_w, gate_b, gates);
    scale_kernel<<<2048, 256, 0, stream>>>(x, gates, out);
}